// Round 1
// baseline (2085.061 us; speedup 1.0000x reference)
//
#include <hip/hip_runtime.h>
#include <cstdint>
#include <cstddef>

#define H 96
#define W 96
#define HW 9216
#define C 256
#define B 8
#define O 256
#define KK 9
#define EPS 1e-5f

#define MT 64        // pixels per block (main kernel)
#define CT 2         // input channels per K-chunk
#define JT (CT*KK)   // 18 ck-steps per chunk

// ---------------- Kernel 1: offset conv (3x3, C=256 -> 27 ch), oc split into 3 groups
__global__ __launch_bounds__(256) void offset_conv_k(
    const float* __restrict__ x, const float* __restrict__ w_off,
    const float* __restrict__ b_off, float* __restrict__ om)
{
    int p = blockIdx.x * 256 + threadIdx.x;   // 0..73727  (pixel index: b*HW + h*W + w)
    int g = blockIdx.y;                       // 0..2 (group of 9 output channels)
    int b = p / HW;
    int rem = p - b * HW;
    int h = rem / W;
    int w = rem - h * W;

    float acc[9];
#pragma unroll
    for (int i = 0; i < 9; ++i) acc[i] = b_off[g * 9 + i];

    const float* xb = x + (size_t)b * C * HW;
    for (int c = 0; c < C; ++c) {
        const float* xc = xb + c * HW;
        float xv[9];
#pragma unroll
        for (int k = 0; k < 9; ++k) {
            int yy = h + k / 3 - 1;
            int xx = w + k % 3 - 1;
            bool ok = (yy >= 0) & (yy < H) & (xx >= 0) & (xx < W);
            xv[k] = ok ? xc[yy * W + xx] : 0.0f;
        }
        // wave-uniform weight indices -> scalar loads
        const float* wc = w_off + (size_t)(g * 9) * C * 9 + c * 9;
#pragma unroll
        for (int oc = 0; oc < 9; ++oc) {
#pragma unroll
            for (int k = 0; k < 9; ++k)
                acc[oc] += xv[k] * wc[(size_t)oc * C * 9 + k];
        }
    }
    float* omp = om + ((size_t)b * 27 + g * 9) * HW + rem;
#pragma unroll
    for (int oc = 0; oc < 9; ++oc) omp[(size_t)oc * HW] = acc[oc];
}

// ---------------- Kernel 2: transpose w_dcn (O=256, CK=2304) -> wT (CK, O)
__global__ __launch_bounds__(256) void transpose_w_k(
    const float* __restrict__ wd, float* __restrict__ wT)
{
    __shared__ float tile[32][33];
    int tx = threadIdx.x;   // 0..31
    int ty = threadIdx.y;   // 0..7
    int ck0 = blockIdx.x * 32;   // 72 blocks
    int o0  = blockIdx.y * 32;   // 8 blocks
#pragma unroll
    for (int i = 0; i < 32; i += 8)
        tile[ty + i][tx] = wd[(size_t)(o0 + ty + i) * 2304 + ck0 + tx];
    __syncthreads();
#pragma unroll
    for (int i = 0; i < 32; i += 8)
        wT[(size_t)(ck0 + ty + i) * O + o0 + tx] = tile[tx][ty + i];
}

// ---------------- Kernel 3: deformable conv main: sample -> GEMM -> BN -> ReLU
__global__ __launch_bounds__(256) void dcn_main_k(
    const float* __restrict__ x, const float* __restrict__ om,
    const float* __restrict__ wT, const float* __restrict__ b_dcn,
    const float* __restrict__ gamma, const float* __restrict__ beta,
    const float* __restrict__ rmean, const float* __restrict__ rvar,
    float* __restrict__ out)
{
    __shared__ int   s_off[MT * KK * 4];   // 4 corner plane offsets per (pixel,k)
    __shared__ float s_wgt[MT * KK * 4];   // 4 corner weights (incl. mask & OOB zero)
    __shared__ float s_a[JT * MT];         // staged sampled values, layout [j][m]

    int t = threadIdx.x;
    int p0 = blockIdx.x * MT;      // first pixel of tile; HW % MT == 0 -> b uniform
    int b = p0 / HW;
    int rem0 = p0 - b * HW;

    // ---- precompute bilinear records: MT*KK = 576 entries
    for (int v = t; v < MT * KK; v += 256) {
        int m = v / KK;
        int k = v - m * KK;
        int rem = rem0 + m;
        int h = rem / W;
        int w = rem - h * W;
        const float* omb = om + (size_t)b * 27 * HW + rem;
        float offy = omb[(size_t)(2 * k) * HW];
        float offx = omb[(size_t)(2 * k + 1) * HW];
        float z    = omb[(size_t)(18 + k) * HW];
        float mval = 1.0f / (1.0f + __expf(-z));
        float py = (float)(h + k / 3 - 1) + offy;
        float px = (float)(w + k % 3 - 1) + offx;
        float fy = floorf(py), fx = floorf(px);
        int y0 = (int)fy, x0 = (int)fx;
        float wy = py - fy, wx = px - fx;
        int r4 = v * 4;
#pragma unroll
        for (int cnr = 0; cnr < 4; ++cnr) {
            int yy = y0 + (cnr >> 1);
            int xx = x0 + (cnr & 1);
            bool ok = (yy >= 0) & (yy < H) & (xx >= 0) & (xx < W);
            float wgt = ((cnr >> 1) ? wy : 1.0f - wy) * ((cnr & 1) ? wx : 1.0f - wx) * mval;
            int yc = min(max(yy, 0), H - 1);
            int xc = min(max(xx, 0), W - 1);
            s_off[r4 + cnr] = yc * W + xc;
            s_wgt[r4 + cnr] = ok ? wgt : 0.0f;
        }
    }

    int tn = t & 31;   // o-group: owns o = tn*8 .. tn*8+7
    int tm = t >> 5;   // m-group: owns m = tm*8 .. tm*8+7
    float acc[8][8];
#pragma unroll
    for (int i = 0; i < 8; ++i)
#pragma unroll
        for (int j = 0; j < 8; ++j) acc[i][j] = 0.0f;

    const float* xb = x + (size_t)b * C * HW;

    for (int c0 = 0; c0 < C; c0 += CT) {
        __syncthreads();   // records ready (iter 0) / prev FMA done
        // ---- stage sampled tile: JT*MT = 1152 values
        for (int v = t; v < JT * MT; v += 256) {
            int j = v >> 6;          // 0..17
            int m = v & 63;
            int cl = j / KK;
            int kk = j - cl * KK;
            const float* xp = xb + (size_t)(c0 + cl) * HW;
            int r4 = (m * KK + kk) * 4;
            int4   o4 = *(const int4*)  &s_off[r4];
            float4 w4 = *(const float4*)&s_wgt[r4];
            float val = xp[o4.x] * w4.x + xp[o4.y] * w4.y
                      + xp[o4.z] * w4.z + xp[o4.w] * w4.w;
            s_a[v] = val;            // s_a[j*64 + m]
        }
        __syncthreads();
        // ---- register outer-product GEMM over this chunk
        const float* wrow = wT + (size_t)c0 * KK * O;
        for (int j = 0; j < JT; ++j) {
            float4 a0 = *(const float4*)&s_a[j * 64 + tm * 8];
            float4 a1 = *(const float4*)&s_a[j * 64 + tm * 8 + 4];
            float4 w0 = *(const float4*)&wrow[(size_t)j * O + tn * 8];
            float4 w1 = *(const float4*)&wrow[(size_t)j * O + tn * 8 + 4];
            float am[8] = {a0.x, a0.y, a0.z, a0.w, a1.x, a1.y, a1.z, a1.w};
            float wo[8] = {w0.x, w0.y, w0.z, w0.w, w1.x, w1.y, w1.z, w1.w};
#pragma unroll
            for (int mi = 0; mi < 8; ++mi)
#pragma unroll
                for (int oi = 0; oi < 8; ++oi)
                    acc[mi][oi] += am[mi] * wo[oi];
        }
    }

    // ---- epilogue: bias + BN + ReLU, float4 stores
    float* outb = out + (size_t)b * O * HW + rem0 + tm * 8;
#pragma unroll
    for (int oi = 0; oi < 8; ++oi) {
        int o = tn * 8 + oi;
        float scale = gamma[o] * rsqrtf(rvar[o] + EPS);
        float shift = (b_dcn[o] - rmean[o]) * scale + beta[o];
        float4 v0, v1;
        v0.x = fmaxf(acc[0][oi] * scale + shift, 0.0f);
        v0.y = fmaxf(acc[1][oi] * scale + shift, 0.0f);
        v0.z = fmaxf(acc[2][oi] * scale + shift, 0.0f);
        v0.w = fmaxf(acc[3][oi] * scale + shift, 0.0f);
        v1.x = fmaxf(acc[4][oi] * scale + shift, 0.0f);
        v1.y = fmaxf(acc[5][oi] * scale + shift, 0.0f);
        v1.z = fmaxf(acc[6][oi] * scale + shift, 0.0f);
        v1.w = fmaxf(acc[7][oi] * scale + shift, 0.0f);
        float* po = outb + (size_t)o * HW;
        *(float4*)po       = v0;
        *(float4*)(po + 4) = v1;
    }
}

extern "C" void kernel_launch(void* const* d_in, const int* in_sizes, int n_in,
                              void* d_out, int out_size, void* d_ws, size_t ws_size,
                              hipStream_t stream) {
    const float* x     = (const float*)d_in[0];
    const float* w_off = (const float*)d_in[1];
    const float* b_off = (const float*)d_in[2];
    const float* w_dcn = (const float*)d_in[3];
    const float* b_dcn = (const float*)d_in[4];
    const float* gamma = (const float*)d_in[5];
    const float* beta  = (const float*)d_in[6];
    const float* rmean = (const float*)d_in[7];
    const float* rvar  = (const float*)d_in[8];
    float* out = (float*)d_out;

    float* om = (float*)d_ws;                        // B*27*HW  = 1,990,656 floats
    float* wT = om + (size_t)B * 27 * HW;            // CK*O     =   589,824 floats

    hipLaunchKernelGGL(offset_conv_k, dim3(288, 3), dim3(256), 0, stream,
                       x, w_off, b_off, om);
    hipLaunchKernelGGL(transpose_w_k, dim3(72, 8), dim3(32, 8), 0, stream,
                       w_dcn, wT);
    hipLaunchKernelGGL(dcn_main_k, dim3(73728 / MT), dim3(256), 0, stream,
                       x, om, wT, b_dcn, gamma, beta, rmean, rvar, out);
}

// Round 2
// 687.865 us; speedup vs baseline: 3.0312x; 3.0312x over previous
//
#include <hip/hip_runtime.h>
#include <hip/hip_bf16.h>
#include <cstdint>
#include <cstddef>

#define H 96
#define W 96
#define HW 9216
#define C 256
#define B 8
#define O 256
#define KK 9
#define EPS 1e-5f

typedef __attribute__((ext_vector_type(8))) short short8;
typedef __attribute__((ext_vector_type(4))) float float4v;
typedef unsigned short ushort_t;
typedef unsigned int uint_t;

// ---------------- Kernel 1: offset conv (3x3, C=256 -> 27 ch), oc split into 3 groups
__global__ __launch_bounds__(256) void offset_conv_k(
    const float* __restrict__ x, const float* __restrict__ w_off,
    const float* __restrict__ b_off, float* __restrict__ om)
{
    int p = blockIdx.x * 256 + threadIdx.x;
    int g = blockIdx.y;
    int b = p / HW;
    int rem = p - b * HW;
    int h = rem / W;
    int w = rem - h * W;

    float acc[9];
#pragma unroll
    for (int i = 0; i < 9; ++i) acc[i] = b_off[g * 9 + i];

    const float* xb = x + (size_t)b * C * HW;
    for (int c = 0; c < C; ++c) {
        const float* xc = xb + c * HW;
        float xv[9];
#pragma unroll
        for (int k = 0; k < 9; ++k) {
            int yy = h + k / 3 - 1;
            int xx = w + k % 3 - 1;
            bool ok = (yy >= 0) & (yy < H) & (xx >= 0) & (xx < W);
            xv[k] = ok ? xc[yy * W + xx] : 0.0f;
        }
        const float* wc = w_off + (size_t)(g * 9) * C * 9 + c * 9;
#pragma unroll
        for (int oc = 0; oc < 9; ++oc) {
#pragma unroll
            for (int k = 0; k < 9; ++k)
                acc[oc] += xv[k] * wc[(size_t)oc * C * 9 + k];
        }
    }
    float* omp = om + ((size_t)b * 27 + g * 9) * HW + rem;
#pragma unroll
    for (int oc = 0; oc < 9; ++oc) omp[(size_t)oc * HW] = acc[oc];
}

// ---------------- Kernel 2: transpose x (B,C,HW) fp32 -> x_t (B,HW,C) bf16
__global__ __launch_bounds__(256) void transpose_x_k(
    const float* __restrict__ x, ushort_t* __restrict__ xt)
{
    __shared__ float tile[64][65];
    int t = threadIdx.x;
    int p0 = blockIdx.x * 64;
    int c0 = blockIdx.y * 64;
    int b  = blockIdx.z;
    {
        int tx = t & 63, ty = t >> 6;   // ty 0..3
        const float* xb = x + ((size_t)b * C + c0 + ty) * HW + p0 + tx;
#pragma unroll
        for (int i = 0; i < 64; i += 4)
            tile[ty + i][tx] = xb[(size_t)i * HW];
    }
    __syncthreads();
    {
        int tc = t & 31, tp = t >> 5;   // tc: c-pair 0..31, tp: row 0..7
        ushort_t* xtb = xt + ((size_t)b * HW + p0) * C + c0;
#pragma unroll
        for (int i = 0; i < 64; i += 8) {
            int p = tp + i;
            float a  = tile[2 * tc][p];
            float bb = tile[2 * tc + 1][p];
            __hip_bfloat162 h2 = __float22bfloat162_rn(make_float2(a, bb));
            uint_t u;
            __builtin_memcpy(&u, &h2, 4);
            *reinterpret_cast<uint_t*>(&xtb[(size_t)p * C + 2 * tc]) = u;
        }
    }
}

// ---------------- Kernel 3: w_dcn (O, C, KK) fp32 -> Bp[kk][o][c] bf16
__global__ __launch_bounds__(256) void prep_b_k(
    const float* __restrict__ wd, ushort_t* __restrict__ bp)
{
    int idx = blockIdx.x * 256 + threadIdx.x;   // 0 .. 9*256*256-1
    int kk = idx / (O * C);
    int r = idx - kk * O * C;
    int o = r >> 8, c = r & 255;
    float v = wd[((size_t)o * C + c) * KK + kk];
    __hip_bfloat16 hh = __float2bfloat16(v);
    ushort_t u;
    __builtin_memcpy(&u, &hh, 2);
    bp[idx] = u;
}

__device__ __forceinline__ void unpack8(uint4 q, float* v) {
    v[0] = __uint_as_float(q.x << 16);
    v[1] = __uint_as_float(q.x & 0xffff0000u);
    v[2] = __uint_as_float(q.y << 16);
    v[3] = __uint_as_float(q.y & 0xffff0000u);
    v[4] = __uint_as_float(q.z << 16);
    v[5] = __uint_as_float(q.z & 0xffff0000u);
    v[6] = __uint_as_float(q.w << 16);
    v[7] = __uint_as_float(q.w & 0xffff0000u);
}

__device__ __forceinline__ uint_t packbf2(float a, float b) {
    __hip_bfloat162 h2 = __float22bfloat162_rn(make_float2(a, b));
    uint_t u;
    __builtin_memcpy(&u, &h2, 4);
    return u;
}

// ---------------- Kernel 4: deformable conv main (MFMA)
// M-tile 64 pixels, N = 256 outputs, K = 2304 ordered k = kk*C + c.
__global__ __launch_bounds__(256) void dcn_main_k(
    const ushort_t* __restrict__ xt, const float* __restrict__ om,
    const ushort_t* __restrict__ bp, const float* __restrict__ b_dcn,
    const float* __restrict__ gamma, const float* __restrict__ beta,
    const float* __restrict__ rmean, const float* __restrict__ rvar,
    float* __restrict__ out)
{
    __shared__ uint4    s_rec[64 * KK][2];   // 18432 B
    __shared__ ushort_t s_a[2][64][40];      // 10240 B (row pad 32->40 vs banks)

    int t = threadIdx.x;
    int p0 = blockIdx.x * 64;
    int b = p0 / HW;
    int rem0 = p0 - b * HW;

    // ---- bilinear records per (pixel m, tap kk)
    for (int v = t; v < 64 * KK; v += 256) {
        int m = v / KK;
        int k = v - m * KK;
        int rem = rem0 + m;
        int h = rem / W;
        int w = rem - h * W;
        const float* omb = om + (size_t)b * 27 * HW + rem;
        float offy = omb[(size_t)(2 * k) * HW];
        float offx = omb[(size_t)(2 * k + 1) * HW];
        float z    = omb[(size_t)(18 + k) * HW];
        float mval = 1.0f / (1.0f + __expf(-z));
        float py = (float)(h + k / 3 - 1) + offy;
        float px = (float)(w + k % 3 - 1) + offx;
        float fy = floorf(py), fx = floorf(px);
        int y0 = (int)fy, x0 = (int)fx;
        float wy = py - fy, wx = px - fx;
        float row0f = (1.0f - wy) * mval * ((y0 >= 0 && y0 < H) ? 1.0f : 0.0f);
        float row1f = wy * mval * ((y0 >= -1 && y0 < H - 1) ? 1.0f : 0.0f);
        int xsel = min(max(x0, 0), W - 2);
        float wxa = (x0 >= 0 && x0 < W) ? (1.0f - wx) : 0.0f;       // corner x0
        float wxb = (x0 >= -1 && x0 < W - 1) ? wx : 0.0f;           // corner x0+1
        int cx0 = min(max(x0, 0), W - 1);
        int cx1 = min(max(x0 + 1, 0), W - 1);
        float wA = ((cx0 == xsel) ? wxa : 0.0f) + ((cx1 == xsel) ? wxb : 0.0f);
        float wB = ((cx0 == xsel + 1) ? wxa : 0.0f) + ((cx1 == xsel + 1) ? wxb : 0.0f);
        int yc0 = min(max(y0, 0), H - 1);
        int yc1 = min(max(y0 + 1, 0), H - 1);
        uint4 r0, r1;
        r0.x = (uint_t)((yc0 * W + xsel) * C);
        r0.y = (uint_t)((yc1 * W + xsel) * C);
        r0.z = __float_as_uint(row0f * wA);
        r0.w = __float_as_uint(row0f * wB);
        r1.x = __float_as_uint(row1f * wA);
        r1.y = __float_as_uint(row1f * wB);
        r1.z = 0; r1.w = 0;
        s_rec[v][0] = r0;
        s_rec[v][1] = r1;
    }

    float4v acc[4][4];
#pragma unroll
    for (int i = 0; i < 4; ++i)
#pragma unroll
        for (int j = 0; j < 4; ++j)
            acc[i][j] = (float4v){0.f, 0.f, 0.f, 0.f};

    const ushort_t* xtb = xt + (size_t)b * HW * C;
    int wv = t >> 6;         // wave 0..3 -> o block
    int l  = t & 63;
    int ln = l & 15;         // n (and A-row m) within 16x16
    int lq = l >> 4;         // quad 0..3 -> k-subgroup
    int sm = t >> 2;         // staging pixel 0..63
    int sc = (t & 3) * 8;    // staging c-sub

    __syncthreads();

    int buf = 0;
    for (int kk = 0; kk < KK; ++kk) {
        uint4 r0 = s_rec[sm * KK + kk][0];
        uint4 r1 = s_rec[sm * KK + kk][1];
        const ushort_t* pr0 = xtb + r0.x + sc;
        const ushort_t* pr1 = xtb + r0.y + sc;
        float wA0 = __uint_as_float(r0.z), wB0 = __uint_as_float(r0.w);
        float wA1 = __uint_as_float(r1.x), wB1 = __uint_as_float(r1.y);
        const ushort_t* bpk = bp + (size_t)kk * O * C + (size_t)(wv * 64 + ln) * C + lq * 8;

        for (int ci = 0; ci < 8; ++ci) {
            int c0 = ci * 32;
            // ---- stage A: 8 channels of one (m,kk) sample per thread
            uint4 q00 = *(const uint4*)(pr0 + c0);
            uint4 q01 = *(const uint4*)(pr0 + c0 + C);
            uint4 q10 = *(const uint4*)(pr1 + c0);
            uint4 q11 = *(const uint4*)(pr1 + c0 + C);
            // ---- B fragments for this chunk (independent; issued early for ILP)
            short8 bfr[4];
#pragma unroll
            for (int nt = 0; nt < 4; ++nt)
                bfr[nt] = *(const short8*)(bpk + (size_t)(nt * 16) * C + c0);

            float v00[8], v01[8], v10[8], v11[8], val[8];
            unpack8(q00, v00); unpack8(q01, v01);
            unpack8(q10, v10); unpack8(q11, v11);
#pragma unroll
            for (int j = 0; j < 8; ++j)
                val[j] = v00[j] * wA0 + v01[j] * wB0 + v10[j] * wA1 + v11[j] * wB1;
            uint4 pk;
            pk.x = packbf2(val[0], val[1]);
            pk.y = packbf2(val[2], val[3]);
            pk.z = packbf2(val[4], val[5]);
            pk.w = packbf2(val[6], val[7]);
            *(uint4*)&s_a[buf][sm][sc] = pk;

            __syncthreads();

            // ---- MFMA phase
            short8 af[4];
#pragma unroll
            for (int mt = 0; mt < 4; ++mt)
                af[mt] = *(const short8*)&s_a[buf][mt * 16 + ln][lq * 8];
#pragma unroll
            for (int mt = 0; mt < 4; ++mt)
#pragma unroll
                for (int nt = 0; nt < 4; ++nt)
                    acc[mt][nt] = __builtin_amdgcn_mfma_f32_16x16x32_bf16(
                        af[mt], bfr[nt], acc[mt][nt], 0, 0, 0);
            buf ^= 1;
        }
    }

    // ---- epilogue: bias + BN + ReLU
#pragma unroll
    for (int nt = 0; nt < 4; ++nt) {
        int o = wv * 64 + nt * 16 + ln;
        float scale = gamma[o] * rsqrtf(rvar[o] + EPS);
        float shift = (b_dcn[o] - rmean[o]) * scale + beta[o];
        float* po = out + ((size_t)b * O + o) * HW + rem0 + lq * 4;
#pragma unroll
        for (int mt = 0; mt < 4; ++mt) {
            float4 vv;
            vv.x = fmaxf(acc[mt][nt].x * scale + shift, 0.0f);
            vv.y = fmaxf(acc[mt][nt].y * scale + shift, 0.0f);
            vv.z = fmaxf(acc[mt][nt].z * scale + shift, 0.0f);
            vv.w = fmaxf(acc[mt][nt].w * scale + shift, 0.0f);
            *(float4*)(po + mt * 16) = vv;
        }
    }
}

extern "C" void kernel_launch(void* const* d_in, const int* in_sizes, int n_in,
                              void* d_out, int out_size, void* d_ws, size_t ws_size,
                              hipStream_t stream) {
    const float* x     = (const float*)d_in[0];
    const float* w_off = (const float*)d_in[1];
    const float* b_off = (const float*)d_in[2];
    const float* w_dcn = (const float*)d_in[3];
    const float* b_dcn = (const float*)d_in[4];
    const float* gamma = (const float*)d_in[5];
    const float* beta  = (const float*)d_in[6];
    const float* rmean = (const float*)d_in[7];
    const float* rvar  = (const float*)d_in[8];
    float* out = (float*)d_out;

    float*    om  = (float*)d_ws;                        // 1,990,656 f  (7.96 MB)
    ushort_t* bpw = (ushort_t*)(om + (size_t)B * 27 * HW);   // 589,824 us (1.18 MB)
    ushort_t* xtw = bpw + (size_t)KK * O * C;            // 18,874,368 us (37.7 MB)

    hipLaunchKernelGGL(offset_conv_k, dim3(288, 3), dim3(256), 0, stream,
                       x, w_off, b_off, om);
    hipLaunchKernelGGL(transpose_x_k, dim3(144, 4, 8), dim3(256), 0, stream,
                       x, xtw);
    hipLaunchKernelGGL(prep_b_k, dim3(2304), dim3(256), 0, stream,
                       w_dcn, bpw);
    hipLaunchKernelGGL(dcn_main_k, dim3(73728 / 64), dim3(256), 0, stream,
                       xtw, om, bpw, b_dcn, gamma, beta, rmean, rvar, out);
}

// Round 3
// 502.691 us; speedup vs baseline: 4.1478x; 1.3684x over previous
//
#include <hip/hip_runtime.h>
#include <hip/hip_bf16.h>
#include <cstdint>
#include <cstddef>

#define H 96
#define W 96
#define HW 9216
#define C 256
#define B 8
#define O 256
#define KK 9
#define EPS 1e-5f

typedef __attribute__((ext_vector_type(8))) short short8;
typedef __attribute__((ext_vector_type(4))) float float4v;
typedef unsigned short ushort_t;
typedef unsigned int uint_t;

// ---------------- Kernel 1: transpose x (B,C,HW) fp32 -> x_t (B,HW,C) bf16
__global__ __launch_bounds__(256) void transpose_x_k(
    const float* __restrict__ x, ushort_t* __restrict__ xt)
{
    __shared__ float tile[64][65];
    int t = threadIdx.x;
    int p0 = blockIdx.x * 64;
    int c0 = blockIdx.y * 64;
    int b  = blockIdx.z;
    {
        int tx = t & 63, ty = t >> 6;   // ty 0..3
        const float* xb = x + ((size_t)b * C + c0 + ty) * HW + p0 + tx;
#pragma unroll
        for (int i = 0; i < 64; i += 4)
            tile[ty + i][tx] = xb[(size_t)i * HW];
    }
    __syncthreads();
    {
        int tc = t & 31, tp = t >> 5;   // tc: c-pair 0..31, tp: row 0..7
        ushort_t* xtb = xt + ((size_t)b * HW + p0) * C + c0;
#pragma unroll
        for (int i = 0; i < 64; i += 8) {
            int p = tp + i;
            float a  = tile[2 * tc][p];
            float bb = tile[2 * tc + 1][p];
            __hip_bfloat162 h2 = __float22bfloat162_rn(make_float2(a, bb));
            uint_t u;
            __builtin_memcpy(&u, &h2, 4);
            *reinterpret_cast<uint_t*>(&xtb[(size_t)p * C + 2 * tc]) = u;
        }
    }
}

// ---------------- Kernel 2: w_dcn (O, C, KK) fp32 -> Bp[kk][o][c] bf16
__global__ __launch_bounds__(256) void prep_b_k(
    const float* __restrict__ wd, ushort_t* __restrict__ bp)
{
    int idx = blockIdx.x * 256 + threadIdx.x;   // 0 .. 9*256*256-1
    int kk = idx / (O * C);
    int r = idx - kk * O * C;
    int o = r >> 8, c = r & 255;
    float v = wd[((size_t)o * C + c) * KK + kk];
    __hip_bfloat16 hh = __float2bfloat16(v);
    ushort_t u;
    __builtin_memcpy(&u, &hh, 2);
    bp[idx] = u;
}

// ---------------- Kernel 3: w_off (27, C, 3, 3) fp32 -> bo[n=32][kk][c] bf16 (pad n)
__global__ __launch_bounds__(256) void prep_bo_k(
    const float* __restrict__ wo, ushort_t* __restrict__ bo)
{
    int idx = blockIdx.x * 256 + threadIdx.x;   // 0 .. 32*9*256-1
    int n = idx / (KK * C);
    int r = idx - n * KK * C;
    int kk = r >> 8, c = r & 255;
    float v = (n < 27) ? wo[((size_t)n * C + c) * KK + kk] : 0.0f;
    __hip_bfloat16 hh = __float2bfloat16(v);
    ushort_t u;
    __builtin_memcpy(&u, &hh, 2);
    bo[idx] = u;
}

// ---------------- Kernel 4: offset conv via MFMA, A-frags loaded directly from x_t
// M=73728 (128 px/block, 32/wave), N=32 (27 real), K=2304 (k = kk*C + c)
__global__ __launch_bounds__(256) void offset_mfma_k(
    const ushort_t* __restrict__ xt, const ushort_t* __restrict__ bo,
    const float* __restrict__ b_off, float* __restrict__ om)
{
    int t = threadIdx.x;
    int wv = t >> 6, l = t & 63;
    int ln = l & 15, lq = l >> 4;
    int p0 = blockIdx.x * 128;            // 128 | HW -> b uniform per block
    int b = p0 / HW;
    int rem0w = p0 - b * HW + wv * 32;    // wave's first pixel within image
    const ushort_t* xtb = xt + (size_t)b * HW * C;

    // per-mt pixel coords for A-rows (m = ln)
    int hh0[2], ww0[2];
#pragma unroll
    for (int mt = 0; mt < 2; ++mt) {
        int rem = rem0w + mt * 16 + ln;
        hh0[mt] = rem / W;
        ww0[mt] = rem - hh0[mt] * W;
    }

    float4v acc[2][2];
#pragma unroll
    for (int i = 0; i < 2; ++i)
#pragma unroll
        for (int j = 0; j < 2; ++j) acc[i][j] = (float4v){0.f, 0.f, 0.f, 0.f};

#pragma unroll
    for (int kk = 0; kk < KK; ++kk) {
        int dy = kk / 3 - 1, dx = kk % 3 - 1;
        const ushort_t* ap[2];
        bool okv[2];
#pragma unroll
        for (int mt = 0; mt < 2; ++mt) {
            int hh = hh0[mt] + dy, ww = ww0[mt] + dx;
            okv[mt] = (hh >= 0) & (hh < H) & (ww >= 0) & (ww < W);
            ap[mt] = xtb + (size_t)(hh * W + ww) * C + lq * 8;
        }
        const ushort_t* bp0 = bo + ((size_t)(0 * 16 + ln) * KK + kk) * C + lq * 8;
        const ushort_t* bp1 = bo + ((size_t)(1 * 16 + ln) * KK + kk) * C + lq * 8;
#pragma unroll
        for (int cc = 0; cc < 8; ++cc) {
            int c0 = cc * 32;
            short8 af[2];
#pragma unroll
            for (int mt = 0; mt < 2; ++mt) {
                short8 v = (short8)0;
                if (okv[mt]) v = *(const short8*)(ap[mt] + c0);
                af[mt] = v;
            }
            short8 bf0 = *(const short8*)(bp0 + c0);
            short8 bf1 = *(const short8*)(bp1 + c0);
#pragma unroll
            for (int mt = 0; mt < 2; ++mt) {
                acc[mt][0] = __builtin_amdgcn_mfma_f32_16x16x32_bf16(af[mt], bf0, acc[mt][0], 0, 0, 0);
                acc[mt][1] = __builtin_amdgcn_mfma_f32_16x16x32_bf16(af[mt], bf1, acc[mt][1], 0, 0, 0);
            }
        }
    }

    // epilogue: D row = lq*4+reg -> pixel, col = ln -> oc
    float* omb = om + (size_t)b * 27 * HW + rem0w;
#pragma unroll
    for (int nt = 0; nt < 2; ++nt) {
        int oc = nt * 16 + ln;
        if (oc < 27) {
            float bv = b_off[oc];
            float* po = omb + (size_t)oc * HW + lq * 4;
#pragma unroll
            for (int mt = 0; mt < 2; ++mt) {
                float4 v;
                v.x = acc[mt][nt].x + bv;
                v.y = acc[mt][nt].y + bv;
                v.z = acc[mt][nt].z + bv;
                v.w = acc[mt][nt].w + bv;
                *(float4*)(po + mt * 16) = v;
            }
        }
    }
}

__device__ __forceinline__ void unpack8(uint4 q, float* v) {
    v[0] = __uint_as_float(q.x << 16);
    v[1] = __uint_as_float(q.x & 0xffff0000u);
    v[2] = __uint_as_float(q.y << 16);
    v[3] = __uint_as_float(q.y & 0xffff0000u);
    v[4] = __uint_as_float(q.z << 16);
    v[5] = __uint_as_float(q.z & 0xffff0000u);
    v[6] = __uint_as_float(q.w << 16);
    v[7] = __uint_as_float(q.w & 0xffff0000u);
}

__device__ __forceinline__ uint_t packbf2(float a, float b) {
    __hip_bfloat162 h2 = __float22bfloat162_rn(make_float2(a, b));
    uint_t u;
    __builtin_memcpy(&u, &h2, 4);
    return u;
}

// ---------------- Kernel 5: deformable conv main (MFMA)
__global__ __launch_bounds__(256) void dcn_main_k(
    const ushort_t* __restrict__ xt, const float* __restrict__ om,
    const ushort_t* __restrict__ bp, const float* __restrict__ b_dcn,
    const float* __restrict__ gamma, const float* __restrict__ beta,
    const float* __restrict__ rmean, const float* __restrict__ rvar,
    float* __restrict__ out)
{
    __shared__ uint4    s_rec[64 * KK][2];   // 18432 B
    __shared__ ushort_t s_a[2][64][40];      // 10240 B

    int t = threadIdx.x;
    int p0 = blockIdx.x * 64;
    int b = p0 / HW;
    int rem0 = p0 - b * HW;

    for (int v = t; v < 64 * KK; v += 256) {
        int m = v / KK;
        int k = v - m * KK;
        int rem = rem0 + m;
        int h = rem / W;
        int w = rem - h * W;
        const float* omb = om + (size_t)b * 27 * HW + rem;
        float offy = omb[(size_t)(2 * k) * HW];
        float offx = omb[(size_t)(2 * k + 1) * HW];
        float z    = omb[(size_t)(18 + k) * HW];
        float mval = 1.0f / (1.0f + __expf(-z));
        float py = (float)(h + k / 3 - 1) + offy;
        float px = (float)(w + k % 3 - 1) + offx;
        float fy = floorf(py), fx = floorf(px);
        int y0 = (int)fy, x0 = (int)fx;
        float wy = py - fy, wx = px - fx;
        float row0f = (1.0f - wy) * mval * ((y0 >= 0 && y0 < H) ? 1.0f : 0.0f);
        float row1f = wy * mval * ((y0 >= -1 && y0 < H - 1) ? 1.0f : 0.0f);
        int xsel = min(max(x0, 0), W - 2);
        float wxa = (x0 >= 0 && x0 < W) ? (1.0f - wx) : 0.0f;
        float wxb = (x0 >= -1 && x0 < W - 1) ? wx : 0.0f;
        int cx0 = min(max(x0, 0), W - 1);
        int cx1 = min(max(x0 + 1, 0), W - 1);
        float wA = ((cx0 == xsel) ? wxa : 0.0f) + ((cx1 == xsel) ? wxb : 0.0f);
        float wB = ((cx0 == xsel + 1) ? wxa : 0.0f) + ((cx1 == xsel + 1) ? wxb : 0.0f);
        int yc0 = min(max(y0, 0), H - 1);
        int yc1 = min(max(y0 + 1, 0), H - 1);
        uint4 r0, r1;
        r0.x = (uint_t)((yc0 * W + xsel) * C);
        r0.y = (uint_t)((yc1 * W + xsel) * C);
        r0.z = __float_as_uint(row0f * wA);
        r0.w = __float_as_uint(row0f * wB);
        r1.x = __float_as_uint(row1f * wA);
        r1.y = __float_as_uint(row1f * wB);
        r1.z = 0; r1.w = 0;
        s_rec[v][0] = r0;
        s_rec[v][1] = r1;
    }

    float4v acc[4][4];
#pragma unroll
    for (int i = 0; i < 4; ++i)
#pragma unroll
        for (int j = 0; j < 4; ++j)
            acc[i][j] = (float4v){0.f, 0.f, 0.f, 0.f};

    const ushort_t* xtb = xt + (size_t)b * HW * C;
    int wv = t >> 6;
    int l  = t & 63;
    int ln = l & 15;
    int lq = l >> 4;
    int sm = t >> 2;
    int sc = (t & 3) * 8;

    __syncthreads();

    int buf = 0;
    for (int kk = 0; kk < KK; ++kk) {
        uint4 r0 = s_rec[sm * KK + kk][0];
        uint4 r1 = s_rec[sm * KK + kk][1];
        const ushort_t* pr0 = xtb + r0.x + sc;
        const ushort_t* pr1 = xtb + r0.y + sc;
        float wA0 = __uint_as_float(r0.z), wB0 = __uint_as_float(r0.w);
        float wA1 = __uint_as_float(r1.x), wB1 = __uint_as_float(r1.y);
        const ushort_t* bpk = bp + (size_t)kk * O * C + (size_t)(wv * 64 + ln) * C + lq * 8;

        for (int ci = 0; ci < 8; ++ci) {
            int c0 = ci * 32;
            uint4 q00 = *(const uint4*)(pr0 + c0);
            uint4 q01 = *(const uint4*)(pr0 + c0 + C);
            uint4 q10 = *(const uint4*)(pr1 + c0);
            uint4 q11 = *(const uint4*)(pr1 + c0 + C);
            short8 bfr[4];
#pragma unroll
            for (int nt = 0; nt < 4; ++nt)
                bfr[nt] = *(const short8*)(bpk + (size_t)(nt * 16) * C + c0);

            float v00[8], v01[8], v10[8], v11[8], val[8];
            unpack8(q00, v00); unpack8(q01, v01);
            unpack8(q10, v10); unpack8(q11, v11);
#pragma unroll
            for (int j = 0; j < 8; ++j)
                val[j] = v00[j] * wA0 + v01[j] * wB0 + v10[j] * wA1 + v11[j] * wB1;
            uint4 pk;
            pk.x = packbf2(val[0], val[1]);
            pk.y = packbf2(val[2], val[3]);
            pk.z = packbf2(val[4], val[5]);
            pk.w = packbf2(val[6], val[7]);
            *(uint4*)&s_a[buf][sm][sc] = pk;

            __syncthreads();

            short8 af[4];
#pragma unroll
            for (int mt = 0; mt < 4; ++mt)
                af[mt] = *(const short8*)&s_a[buf][mt * 16 + ln][lq * 8];
#pragma unroll
            for (int mt = 0; mt < 4; ++mt)
#pragma unroll
                for (int nt = 0; nt < 4; ++nt)
                    acc[mt][nt] = __builtin_amdgcn_mfma_f32_16x16x32_bf16(
                        af[mt], bfr[nt], acc[mt][nt], 0, 0, 0);
            buf ^= 1;
        }
    }

#pragma unroll
    for (int nt = 0; nt < 4; ++nt) {
        int o = wv * 64 + nt * 16 + ln;
        float scale = gamma[o] * rsqrtf(rvar[o] + EPS);
        float shift = (b_dcn[o] - rmean[o]) * scale + beta[o];
        float* po = out + ((size_t)b * O + o) * HW + rem0 + lq * 4;
#pragma unroll
        for (int mt = 0; mt < 4; ++mt) {
            float4 vv;
            vv.x = fmaxf(acc[mt][nt].x * scale + shift, 0.0f);
            vv.y = fmaxf(acc[mt][nt].y * scale + shift, 0.0f);
            vv.z = fmaxf(acc[mt][nt].z * scale + shift, 0.0f);
            vv.w = fmaxf(acc[mt][nt].w * scale + shift, 0.0f);
            *(float4*)(po + mt * 16) = vv;
        }
    }
}

extern "C" void kernel_launch(void* const* d_in, const int* in_sizes, int n_in,
                              void* d_out, int out_size, void* d_ws, size_t ws_size,
                              hipStream_t stream) {
    const float* x     = (const float*)d_in[0];
    const float* w_off = (const float*)d_in[1];
    const float* b_off = (const float*)d_in[2];
    const float* w_dcn = (const float*)d_in[3];
    const float* b_dcn = (const float*)d_in[4];
    const float* gamma = (const float*)d_in[5];
    const float* beta  = (const float*)d_in[6];
    const float* rmean = (const float*)d_in[7];
    const float* rvar  = (const float*)d_in[8];
    float* out = (float*)d_out;

    float*    om  = (float*)d_ws;                          // 1,990,656 f (7.96 MB)
    ushort_t* bpw = (ushort_t*)(om + (size_t)B * 27 * HW); // 589,824 us (1.18 MB)
    ushort_t* bow = bpw + (size_t)KK * O * C;              // 73,728 us (147 KB)
    ushort_t* xtw = bow + (size_t)32 * KK * C;             // 18,874,368 us (37.7 MB)

    hipLaunchKernelGGL(transpose_x_k, dim3(144, 4, 8), dim3(256), 0, stream,
                       x, xtw);
    hipLaunchKernelGGL(prep_b_k, dim3(2304), dim3(256), 0, stream,
                       w_dcn, bpw);
    hipLaunchKernelGGL(prep_bo_k, dim3(288), dim3(256), 0, stream,
                       w_off, bow);
    hipLaunchKernelGGL(offset_mfma_k, dim3(73728 / 128), dim3(256), 0, stream,
                       xtw, bow, b_off, om);
    hipLaunchKernelGGL(dcn_main_k, dim3(73728 / 64), dim3(256), 0, stream,
                       xtw, om, bpw, b_dcn, gamma, beta, rmean, rvar, out);
}